// Round 1
// baseline (2466.227 us; speedup 1.0000x reference)
//
#include <hip/hip_runtime.h>
#include <stdint.h>

// Problem constants (B,T,H,V) = (4,1024,2048,32000)
#define M_TOK 4096
#define N_VOC 32000
#define K_DIM 2048
#define BM 128
#define BN 128
#define BK 64
#define BETA 0.1f

typedef __bf16 bf16x8 __attribute__((ext_vector_type(8)));
typedef float f32x4 __attribute__((ext_vector_type(4)));

// RNE fp32 -> bf16 (bit pattern as ushort)
__device__ __forceinline__ unsigned short f2bf(float f) {
  unsigned u = __float_as_uint(f);
  u += 0x7FFFu + ((u >> 16) & 1u);
  return (unsigned short)(u >> 16);
}

__global__ __launch_bounds__(256) void cast_f32_bf16(const float* __restrict__ in,
                                                     ushort* __restrict__ out, int n4) {
  int i = blockIdx.x * blockDim.x + threadIdx.x;
  int stride = gridDim.x * blockDim.x;
  const float4* in4 = (const float4*)in;
  ushort4* out4 = (ushort4*)out;
  for (; i < n4; i += stride) {
    float4 f = in4[i];
    ushort4 o;
    o.x = f2bf(f.x);
    o.y = f2bf(f.y);
    o.z = f2bf(f.z);
    o.w = f2bf(f.w);
    out4[i] = o;
  }
}

// C = A(M,K) @ B(N,K)^T, reduced over N on the fly:
//   S[m] += sum_n exp(C[m,n]);  L[m] += sum_n C[m,n];  sel[m] = C[m, ids[m]]
__global__ __launch_bounds__(256) void gemm_stats(
    const ushort* __restrict__ A,   // [M_TOK][K_DIM] bf16 bits
    const ushort* __restrict__ B,   // [N_VOC][K_DIM] bf16 bits
    const int* __restrict__ ids,    // [M_TOK]
    float* __restrict__ S, float* __restrict__ L, float* __restrict__ sel) {
  __shared__ ushort lA[BM * BK];  // 16 KB, unpadded (global_load_lds requirement)
  __shared__ ushort lB[BN * BK];  // 16 KB

  const int tid = threadIdx.x;
  const int wid = tid >> 6;
  const int lane = tid & 63;
  const int m0 = blockIdx.y * BM;
  const int n0 = blockIdx.x * BN;
  const int wr = wid >> 1, wc = wid & 1;  // wave 2x2 grid over 128x128 tile
  const int l15 = lane & 15, quad = lane >> 4;

  // staging coords: each global_load_lds call moves 64 lanes x 16B = 1KB = 8 rows of 64 bf16
  const int sRow = lane >> 3;       // 0..7
  const int sCol = (lane & 7) * 8;  // element col

  f32x4 acc[4][4];
  const f32x4 zero = {0.f, 0.f, 0.f, 0.f};
#pragma unroll
  for (int i = 0; i < 4; ++i)
#pragma unroll
    for (int j = 0; j < 4; ++j) acc[i][j] = zero;

  for (int k0 = 0; k0 < K_DIM; k0 += BK) {
#pragma unroll
    for (int q = 0; q < 4; ++q) {
      int seg = wid * 4 + q;        // 0..15, wave-uniform
      int row = seg * 8 + sRow;     // 0..127
      const ushort* ga = A + (size_t)(m0 + row) * K_DIM + k0 + sCol;
      const ushort* gb = B + (size_t)(n0 + row) * K_DIM + k0 + sCol;
      __builtin_amdgcn_global_load_lds(
          (const __attribute__((address_space(1))) unsigned int*)ga,
          (__attribute__((address_space(3))) unsigned int*)(&lA[seg * 512]), 16, 0, 0);
      __builtin_amdgcn_global_load_lds(
          (const __attribute__((address_space(1))) unsigned int*)gb,
          (__attribute__((address_space(3))) unsigned int*)(&lB[seg * 512]), 16, 0, 0);
    }
    __syncthreads();  // drains vmcnt before LDS reads
#pragma unroll
    for (int ks = 0; ks < 2; ++ks) {
      bf16x8 af[4], bfr[4];
#pragma unroll
      for (int i = 0; i < 4; ++i)
        af[i] = *(const bf16x8*)&lA[(wr * 64 + i * 16 + l15) * BK + ks * 32 + quad * 8];
#pragma unroll
      for (int j = 0; j < 4; ++j)
        bfr[j] = *(const bf16x8*)&lB[(wc * 64 + j * 16 + l15) * BK + ks * 32 + quad * 8];
#pragma unroll
      for (int i = 0; i < 4; ++i)
#pragma unroll
        for (int j = 0; j < 4; ++j)
          acc[i][j] = __builtin_amdgcn_mfma_f32_16x16x32_bf16(af[i], bfr[j], acc[i][j], 0, 0, 0);
    }
    __syncthreads();
  }

  // Epilogue. C/D layout (verified m89/m91): col = lane&15, row = quad*4 + reg.
  // Lane owns rows {wr*64 + i*16 + quad*4 + r}, cols {n0 + wc*64 + j*16 + l15}.
#pragma unroll
  for (int i = 0; i < 4; ++i) {
#pragma unroll
    for (int r = 0; r < 4; ++r) {
      int row = m0 + wr * 64 + i * 16 + quad * 4 + r;
      int sid = ids[row];
      int loc = sid - n0 - wc * 64;
      bool hit = (loc >= 0) && (loc < 64) && ((loc & 15) == l15);
      float es = 0.f, ls = 0.f, selv = 0.f;
#pragma unroll
      for (int j = 0; j < 4; ++j) {
        float v = acc[i][j][r];
        es += __expf(v);
        ls += v;
        if (hit && ((loc >> 4) == j)) selv = v;
      }
      if (hit) sel[row] = selv;  // unique writer across grid
      // butterfly across the quad's 16 lanes (masks < 16 stay in-group)
#pragma unroll
      for (int mk = 1; mk < 16; mk <<= 1) {
        es += __shfl_xor(es, mk);
        ls += __shfl_xor(ls, mk);
      }
      if (l15 == 0) {
        atomicAdd(&S[row], es);
        atomicAdd(&L[row], ls);
      }
    }
  }
}

__global__ __launch_bounds__(1024) void finalize_kernel(
    const float* __restrict__ S1, const float* __restrict__ L1, const float* __restrict__ P1,
    const float* __restrict__ S2, const float* __restrict__ P2,
    const float* __restrict__ mask, const float* __restrict__ adv, float* __restrict__ out) {
  __shared__ float red[12];
  int tid = threadIdx.x;
  int lane = tid & 63;
  if (tid < 12) red[tid] = 0.f;
  __syncthreads();

  float loss_num = 0.f, mask_sum = 0.f, ptl_sum = 0.f, lpm_sum = 0.f;
  float klb[4] = {0.f, 0.f, 0.f, 0.f}, mb[4] = {0.f, 0.f, 0.f, 0.f};
#pragma unroll
  for (int k = 0; k < 4; ++k) {
    int t = k * 1024 + tid;  // batch index b == k exactly
    float lse1 = logf(S1[t]);
    float ptl = P1[t] - lse1;
    float ref_ptl = P2[t] - logf(S2[t]);
    float d = ref_ptl - ptl;
    float kl = expf(d) - d - 1.f;
    float m = mask[t];
    float a = adv[k];
    // coef_1 = exp(ptl - stopgrad(ptl)) = 1; coef_2 = clip(1,...) = 1
    // per_token_loss = -min(adv, adv) + BETA*kl = -adv + BETA*kl
    loss_num += (-a + BETA * kl) * m;
    mask_sum += m;
    ptl_sum += ptl;
    lpm_sum += L1[t] * (1.f / (float)N_VOC) - lse1;
    klb[k] += kl * m;
    mb[k] += m;
  }
  float vals[12] = {loss_num, mask_sum, ptl_sum, lpm_sum,
                    klb[0], klb[1], klb[2], klb[3],
                    mb[0],  mb[1],  mb[2],  mb[3]};
#pragma unroll
  for (int v = 0; v < 12; ++v) {
    float xv = vals[v];
#pragma unroll
    for (int mk = 32; mk >= 1; mk >>= 1) xv += __shfl_xor(xv, mk);
    if (lane == 0) atomicAdd(&red[v], xv);
  }
  __syncthreads();
  if (tid == 0) {
    float loss = red[0] / fmaxf(red[1], 1.f);
    float km = 0.f;
#pragma unroll
    for (int b = 0; b < 4; ++b) km += red[4 + b] / fmaxf(red[8 + b], 1.f);
    out[0] = loss;                       // loss
    out[1] = red[2] * (1.f / 4096.f);    // per_token_logps.mean()
    out[2] = red[3] * (1.f / 4096.f);    // log_probs.mean()
    out[3] = km * 0.25f;                 // kl_metric
  }
}

extern "C" void kernel_launch(void* const* d_in, const int* in_sizes, int n_in,
                              void* d_out, int out_size, void* d_ws, size_t ws_size,
                              hipStream_t stream) {
  const float* x = (const float*)d_in[0];
  const float* W = (const float*)d_in[1];
  const float* ref_W = (const float*)d_in[2];
  const float* ref_x = (const float*)d_in[3];
  const int* ids = (const int*)d_in[4];
  const float* mask = (const float*)d_in[5];
  const float* adv = (const float*)d_in[6];
  float* out = (float*)d_out;

  // Workspace layout: [ Wbf 131MB | xbf 16.8MB | accum 96KB ]  (~148MB)
  char* ws = (char*)d_ws;
  ushort* Wbf = (ushort*)ws;
  ushort* xbf = (ushort*)(ws + (size_t)N_VOC * K_DIM * 2);
  float* accum = (float*)(ws + (size_t)N_VOC * K_DIM * 2 + (size_t)M_TOK * K_DIM * 2);
  float* S1 = accum;
  float* L1 = accum + 4096;
  float* P1 = accum + 8192;
  float* S2 = accum + 12288;
  float* L2 = accum + 16384;
  float* P2 = accum + 20480;

  hipMemsetAsync(accum, 0, 6 * 4096 * sizeof(float), stream);

  dim3 grid(N_VOC / BN, M_TOK / BM);  // 250 x 32

  cast_f32_bf16<<<2048, 256, 0, stream>>>(W, Wbf, N_VOC * K_DIM / 4);
  cast_f32_bf16<<<512, 256, 0, stream>>>(x, xbf, M_TOK * K_DIM / 4);
  gemm_stats<<<grid, 256, 0, stream>>>(xbf, Wbf, ids, S1, L1, P1);

  // W buffer reused for ref (stream-ordered after gemm 1)
  cast_f32_bf16<<<2048, 256, 0, stream>>>(ref_W, Wbf, N_VOC * K_DIM / 4);
  cast_f32_bf16<<<512, 256, 0, stream>>>(ref_x, xbf, M_TOK * K_DIM / 4);
  gemm_stats<<<grid, 256, 0, stream>>>(xbf, Wbf, ids, S2, L2, P2);

  finalize_kernel<<<1, 1024, 0, stream>>>(S1, L1, P1, S2, P2, mask, adv, out);
}

// Round 2
// 2261.523 us; speedup vs baseline: 1.0905x; 1.0905x over previous
//
#include <hip/hip_runtime.h>
#include <stdint.h>

// Problem constants (B,T,H,V) = (4,1024,2048,32000)
#define M_TOK 4096
#define N_VOC 32000
#define K_DIM 2048
#define BM 128
#define BN 128
#define BK 64
#define BETA 0.1f

typedef __bf16 bf16x8 __attribute__((ext_vector_type(8)));
typedef float f32x4 __attribute__((ext_vector_type(4)));

// RNE fp32 -> bf16 (bit pattern as ushort)
__device__ __forceinline__ unsigned short f2bf(float f) {
  unsigned u = __float_as_uint(f);
  u += 0x7FFFu + ((u >> 16) & 1u);
  return (unsigned short)(u >> 16);
}

__global__ __launch_bounds__(256) void cast_f32_bf16(const float* __restrict__ in,
                                                     ushort* __restrict__ out, int n4) {
  int i = blockIdx.x * blockDim.x + threadIdx.x;
  int stride = gridDim.x * blockDim.x;
  const float4* in4 = (const float4*)in;
  ushort4* out4 = (ushort4*)out;
  for (; i < n4; i += stride) {
    float4 f = in4[i];
    ushort4 o;
    o.x = f2bf(f.x);
    o.y = f2bf(f.y);
    o.z = f2bf(f.z);
    o.w = f2bf(f.w);
    out4[i] = o;
  }
}

// C = A(M,K) @ B(N,K)^T, reduced over N on the fly:
//   S[m] += sum_n exp(C[m,n]);  L[m] += sum_n C[m,n];  sel[m] = C[m, ids[m]]
//
// LDS layout uses an XOR chunk swizzle: global 16B-chunk g of row r is stored
// at LDS chunk position g ^ (r & 7). This spreads the fragment-read banks
// (row stride = 128 B = all 32 banks aliased) so each 8-lane service group
// covers all 32 banks exactly once. global_load_lds destinations stay
// contiguous (wave-uniform base + lane*16), as required.
__global__ __launch_bounds__(256) void gemm_stats(
    const ushort* __restrict__ A,   // [M_TOK][K_DIM] bf16 bits
    const ushort* __restrict__ B,   // [N_VOC][K_DIM] bf16 bits
    const int* __restrict__ ids,    // [M_TOK]
    float* __restrict__ S, float* __restrict__ L, float* __restrict__ sel) {
  __shared__ ushort lA[BM * BK];  // 16 KB
  __shared__ ushort lB[BN * BK];  // 16 KB

  const int tid = threadIdx.x;
  const int wid = tid >> 6;
  const int lane = tid & 63;
  const int m0 = blockIdx.y * BM;
  const int n0 = blockIdx.x * BN;
  const int wr = wid >> 1, wc = wid & 1;  // wave 2x2 grid over 128x128 tile
  const int l15 = lane & 15, quad = lane >> 4;

  // staging coords: each global_load_lds call moves 64 lanes x 16B = 1KB = 8 rows of 64 bf16
  const int sRow = lane >> 3;                    // 0..7 (== row & 7)
  const int sChunk = (lane & 7) ^ sRow;          // swizzled SOURCE chunk for this lane
  const int sCol = sChunk * 8;                   // element col within BK slice

  f32x4 acc[4][4];
  const f32x4 zero = {0.f, 0.f, 0.f, 0.f};
#pragma unroll
  for (int i = 0; i < 4; ++i)
#pragma unroll
    for (int j = 0; j < 4; ++j) acc[i][j] = zero;

  for (int k0 = 0; k0 < K_DIM; k0 += BK) {
#pragma unroll
    for (int q = 0; q < 4; ++q) {
      int seg = wid * 4 + q;        // 0..15, wave-uniform
      int row = seg * 8 + sRow;     // 0..127
      const ushort* ga = A + (size_t)(m0 + row) * K_DIM + k0 + sCol;
      const ushort* gb = B + (size_t)(n0 + row) * K_DIM + k0 + sCol;
      __builtin_amdgcn_global_load_lds(
          (const __attribute__((address_space(1))) unsigned int*)ga,
          (__attribute__((address_space(3))) unsigned int*)(&lA[seg * 512]), 16, 0, 0);
      __builtin_amdgcn_global_load_lds(
          (const __attribute__((address_space(1))) unsigned int*)gb,
          (__attribute__((address_space(3))) unsigned int*)(&lB[seg * 512]), 16, 0, 0);
    }
    __syncthreads();  // drains vmcnt before LDS reads
#pragma unroll
    for (int ks = 0; ks < 2; ++ks) {
      bf16x8 af[4], bfr[4];
#pragma unroll
      for (int i = 0; i < 4; ++i) {
        int r = wr * 64 + i * 16 + l15;
        int c = ((ks * 4 + quad) ^ (l15 & 7)) * 8;  // swizzled LDS chunk
        af[i] = *(const bf16x8*)&lA[r * BK + c];
      }
#pragma unroll
      for (int j = 0; j < 4; ++j) {
        int r = wc * 64 + j * 16 + l15;
        int c = ((ks * 4 + quad) ^ (l15 & 7)) * 8;
        bfr[j] = *(const bf16x8*)&lB[r * BK + c];
      }
#pragma unroll
      for (int i = 0; i < 4; ++i)
#pragma unroll
        for (int j = 0; j < 4; ++j)
          acc[i][j] = __builtin_amdgcn_mfma_f32_16x16x32_bf16(af[i], bfr[j], acc[i][j], 0, 0, 0);
    }
    __syncthreads();
  }

  // Epilogue. C/D layout (verified m89/m91): col = lane&15, row = quad*4 + reg.
  // Lane owns rows {wr*64 + i*16 + quad*4 + r}, cols {n0 + wc*64 + j*16 + l15}.
#pragma unroll
  for (int i = 0; i < 4; ++i) {
#pragma unroll
    for (int r = 0; r < 4; ++r) {
      int row = m0 + wr * 64 + i * 16 + quad * 4 + r;
      int sid = ids[row];
      int loc = sid - n0 - wc * 64;
      bool hit = (loc >= 0) && (loc < 64) && ((loc & 15) == l15);
      float es = 0.f, ls = 0.f, selv = 0.f;
#pragma unroll
      for (int j = 0; j < 4; ++j) {
        float v = acc[i][j][r];
        es += __expf(v);
        ls += v;
        if (hit && ((loc >> 4) == j)) selv = v;
      }
      if (hit) sel[row] = selv;  // unique writer across grid
      // butterfly across the quad's 16 lanes (masks < 16 stay in-group)
#pragma unroll
      for (int mk = 1; mk < 16; mk <<= 1) {
        es += __shfl_xor(es, mk);
        ls += __shfl_xor(ls, mk);
      }
      if (l15 == 0) {
        atomicAdd(&S[row], es);
        atomicAdd(&L[row], ls);
      }
    }
  }
}

__global__ __launch_bounds__(1024) void finalize_kernel(
    const float* __restrict__ S1, const float* __restrict__ L1, const float* __restrict__ P1,
    const float* __restrict__ S2, const float* __restrict__ P2,
    const float* __restrict__ mask, const float* __restrict__ adv, float* __restrict__ out) {
  __shared__ float red[12];
  int tid = threadIdx.x;
  int lane = tid & 63;
  if (tid < 12) red[tid] = 0.f;
  __syncthreads();

  float loss_num = 0.f, mask_sum = 0.f, ptl_sum = 0.f, lpm_sum = 0.f;
  float klb[4] = {0.f, 0.f, 0.f, 0.f}, mb[4] = {0.f, 0.f, 0.f, 0.f};
#pragma unroll
  for (int k = 0; k < 4; ++k) {
    int t = k * 1024 + tid;  // batch index b == k exactly
    float lse1 = logf(S1[t]);
    float ptl = P1[t] - lse1;
    float ref_ptl = P2[t] - logf(S2[t]);
    float d = ref_ptl - ptl;
    float kl = expf(d) - d - 1.f;
    float m = mask[t];
    float a = adv[k];
    // coef_1 = exp(ptl - stopgrad(ptl)) = 1; coef_2 = clip(1,...) = 1
    // per_token_loss = -min(adv, adv) + BETA*kl = -adv + BETA*kl
    loss_num += (-a + BETA * kl) * m;
    mask_sum += m;
    ptl_sum += ptl;
    lpm_sum += L1[t] * (1.f / (float)N_VOC) - lse1;
    klb[k] += kl * m;
    mb[k] += m;
  }
  float vals[12] = {loss_num, mask_sum, ptl_sum, lpm_sum,
                    klb[0], klb[1], klb[2], klb[3],
                    mb[0],  mb[1],  mb[2],  mb[3]};
#pragma unroll
  for (int v = 0; v < 12; ++v) {
    float xv = vals[v];
#pragma unroll
    for (int mk = 32; mk >= 1; mk >>= 1) xv += __shfl_xor(xv, mk);
    if (lane == 0) atomicAdd(&red[v], xv);
  }
  __syncthreads();
  if (tid == 0) {
    float loss = red[0] / fmaxf(red[1], 1.f);
    float km = 0.f;
#pragma unroll
    for (int b = 0; b < 4; ++b) km += red[4 + b] / fmaxf(red[8 + b], 1.f);
    out[0] = loss;                       // loss
    out[1] = red[2] * (1.f / 4096.f);    // per_token_logps.mean()
    out[2] = red[3] * (1.f / 4096.f);    // log_probs.mean()
    out[3] = km * 0.25f;                 // kl_metric
  }
}

extern "C" void kernel_launch(void* const* d_in, const int* in_sizes, int n_in,
                              void* d_out, int out_size, void* d_ws, size_t ws_size,
                              hipStream_t stream) {
  const float* x = (const float*)d_in[0];
  const float* W = (const float*)d_in[1];
  const float* ref_W = (const float*)d_in[2];
  const float* ref_x = (const float*)d_in[3];
  const int* ids = (const int*)d_in[4];
  const float* mask = (const float*)d_in[5];
  const float* adv = (const float*)d_in[6];
  float* out = (float*)d_out;

  // Workspace layout: [ Wbf 131MB | xbf 16.8MB | accum 96KB ]  (~148MB)
  char* ws = (char*)d_ws;
  ushort* Wbf = (ushort*)ws;
  ushort* xbf = (ushort*)(ws + (size_t)N_VOC * K_DIM * 2);
  float* accum = (float*)(ws + (size_t)N_VOC * K_DIM * 2 + (size_t)M_TOK * K_DIM * 2);
  float* S1 = accum;
  float* L1 = accum + 4096;
  float* P1 = accum + 8192;
  float* S2 = accum + 12288;
  float* L2 = accum + 16384;
  float* P2 = accum + 20480;

  hipMemsetAsync(accum, 0, 6 * 4096 * sizeof(float), stream);

  dim3 grid(N_VOC / BN, M_TOK / BM);  // 250 x 32

  cast_f32_bf16<<<2048, 256, 0, stream>>>(W, Wbf, N_VOC * K_DIM / 4);
  cast_f32_bf16<<<512, 256, 0, stream>>>(x, xbf, M_TOK * K_DIM / 4);
  gemm_stats<<<grid, 256, 0, stream>>>(xbf, Wbf, ids, S1, L1, P1);

  // W buffer reused for ref (stream-ordered after gemm 1)
  cast_f32_bf16<<<2048, 256, 0, stream>>>(ref_W, Wbf, N_VOC * K_DIM / 4);
  cast_f32_bf16<<<512, 256, 0, stream>>>(ref_x, xbf, M_TOK * K_DIM / 4);
  gemm_stats<<<grid, 256, 0, stream>>>(xbf, Wbf, ids, S2, L2, P2);

  finalize_kernel<<<1, 1024, 0, stream>>>(S1, L1, P1, S2, P2, mask, adv, out);
}

// Round 3
// 1981.962 us; speedup vs baseline: 1.2443x; 1.1411x over previous
//
#include <hip/hip_runtime.h>
#include <stdint.h>

// Problem constants (B,T,H,V) = (4,1024,2048,32000)
#define M_TOK 4096
#define N_VOC 32000
#define K_DIM 2048
#define BM 128
#define BN 128
#define BK 64
#define BETA 0.1f
#define W_SCALE 32.0f
#define INV_W_SCALE (1.0f / 32.0f)

typedef float f32x4 __attribute__((ext_vector_type(4)));

// fp32 -> fp8 e4m3 (OCP) cast with static scale, 8 elements per thread
__global__ __launch_bounds__(256) void cast_f32_fp8(const float* __restrict__ in,
                                                    uint2* __restrict__ out, int n8,
                                                    float scale) {
  int i = blockIdx.x * blockDim.x + threadIdx.x;
  int stride = gridDim.x * blockDim.x;
  const float4* in4 = (const float4*)in;
  for (; i < n8; i += stride) {
    float4 f0 = in4[2 * i];
    float4 f1 = in4[2 * i + 1];
    int lo = __builtin_amdgcn_cvt_pk_fp8_f32(f0.x * scale, f0.y * scale, 0, false);
    lo = __builtin_amdgcn_cvt_pk_fp8_f32(f0.z * scale, f0.w * scale, lo, true);
    int hi = __builtin_amdgcn_cvt_pk_fp8_f32(f1.x * scale, f1.y * scale, 0, false);
    hi = __builtin_amdgcn_cvt_pk_fp8_f32(f1.z * scale, f1.w * scale, hi, true);
    uint2 o;
    o.x = (unsigned)lo;
    o.y = (unsigned)hi;
    out[i] = o;
  }
}

// C = A(M,K) @ B(N,K)^T in fp8 e4m3 (B pre-scaled by W_SCALE; acc *= 1/W_SCALE),
// reduced over N on the fly:
//   S[m] += sum_n exp(C[m,n]);  L[m] += sum_n C[m,n];  sel[m] = C[m, ids[m]]
//
// LDS rows are 64 fp8 = 64 B = 4 x 16B chunks. XOR swizzle: global chunk g of
// row r is stored at LDS chunk g ^ ((r>>1)&3). This makes both the staging
// writes (lane-contiguous, as global_load_lds requires) and the b64 fragment
// reads (16 lanes x 8 B) cover the 32 banks with only free 2-way aliasing.
__global__ __launch_bounds__(256) void gemm_stats(
    const unsigned char* __restrict__ A,   // [M_TOK][K_DIM] fp8
    const unsigned char* __restrict__ B,   // [N_VOC][K_DIM] fp8 (scaled by W_SCALE)
    const int* __restrict__ ids,           // [M_TOK]
    float* __restrict__ S, float* __restrict__ L, float* __restrict__ sel) {
  __shared__ unsigned char lA[BM * BK];  // 8 KB
  __shared__ unsigned char lB[BN * BK];  // 8 KB

  const int tid = threadIdx.x;
  const int wid = tid >> 6;
  const int lane = tid & 63;
  const int m0 = blockIdx.y * BM;
  const int n0 = blockIdx.x * BN;
  const int wr = wid >> 1, wc = wid & 1;  // wave 2x2 grid over 128x128 tile
  const int l15 = lane & 15, quad = lane >> 4;

  // staging coords: each global_load_lds call moves 64 lanes x 16B = 1KB = 16 rows of 64 fp8
  const int sRow = lane >> 2;                          // 0..15
  const int sChunk = (lane & 3) ^ ((sRow >> 1) & 3);   // swizzled SOURCE chunk
  const int sCol = sChunk * 16;                        // byte/elem col within BK slice

  f32x4 acc[4][4];
  const f32x4 zero = {0.f, 0.f, 0.f, 0.f};
#pragma unroll
  for (int i = 0; i < 4; ++i)
#pragma unroll
    for (int j = 0; j < 4; ++j) acc[i][j] = zero;

  // hoisted swizzled LDS fragment byte offsets (row-local part added in loop)
  const int swzkey = (l15 >> 1) & 3;

  for (int k0 = 0; k0 < K_DIM; k0 += BK) {
#pragma unroll
    for (int q = 0; q < 2; ++q) {
      int seg = wid * 2 + q;        // 0..7, wave-uniform
      int row = seg * 16 + sRow;    // 0..127
      const unsigned char* ga = A + (size_t)(m0 + row) * K_DIM + k0 + sCol;
      const unsigned char* gb = B + (size_t)(n0 + row) * K_DIM + k0 + sCol;
      __builtin_amdgcn_global_load_lds(
          (const __attribute__((address_space(1))) unsigned int*)ga,
          (__attribute__((address_space(3))) unsigned int*)(&lA[seg * 1024]), 16, 0, 0);
      __builtin_amdgcn_global_load_lds(
          (const __attribute__((address_space(1))) unsigned int*)gb,
          (__attribute__((address_space(3))) unsigned int*)(&lB[seg * 1024]), 16, 0, 0);
    }
    __syncthreads();  // drains vmcnt before LDS reads
#pragma unroll
    for (int ks = 0; ks < 2; ++ks) {
      long long af[4], bfr[4];
      // global chunk for this lane's 8-byte fragment: ks*2 + (quad>>1); within-chunk: (quad&1)*8
      const int cg = ks * 2 + (quad >> 1);
      const int coff = ((cg ^ swzkey) * 16) + (quad & 1) * 8;
#pragma unroll
      for (int i = 0; i < 4; ++i) {
        int r = wr * 64 + i * 16 + l15;
        af[i] = *(const long long*)&lA[r * BK + coff];
      }
#pragma unroll
      for (int j = 0; j < 4; ++j) {
        int r = wc * 64 + j * 16 + l15;
        bfr[j] = *(const long long*)&lB[r * BK + coff];
      }
#pragma unroll
      for (int i = 0; i < 4; ++i)
#pragma unroll
        for (int j = 0; j < 4; ++j)
          acc[i][j] = __builtin_amdgcn_mfma_f32_16x16x32_fp8_fp8(af[i], bfr[j], acc[i][j], 0, 0, 0);
    }
    __syncthreads();
  }

  // Epilogue. C/D layout (dtype-independent, m89/m121): col = lane&15, row = quad*4 + reg.
  // Lane owns rows {wr*64 + i*16 + quad*4 + r}, cols {n0 + wc*64 + j*16 + l15}.
  // Logits were computed against W*W_SCALE -> multiply by INV_W_SCALE.
#pragma unroll
  for (int i = 0; i < 4; ++i) {
#pragma unroll
    for (int r = 0; r < 4; ++r) {
      int row = m0 + wr * 64 + i * 16 + quad * 4 + r;
      int sid = ids[row];
      int loc = sid - n0 - wc * 64;
      bool hit = (loc >= 0) && (loc < 64) && ((loc & 15) == l15);
      float es = 0.f, ls = 0.f, selv = 0.f;
#pragma unroll
      for (int j = 0; j < 4; ++j) {
        float v = acc[i][j][r] * INV_W_SCALE;
        es += __expf(v);
        ls += v;
        if (hit && ((loc >> 4) == j)) selv = v;
      }
      if (hit) sel[row] = selv;  // unique writer across grid
      // butterfly across the quad's 16 lanes (masks < 16 stay in-group)
#pragma unroll
      for (int mk = 1; mk < 16; mk <<= 1) {
        es += __shfl_xor(es, mk);
        ls += __shfl_xor(ls, mk);
      }
      if (l15 == 0) {
        atomicAdd(&S[row], es);
        atomicAdd(&L[row], ls);
      }
    }
  }
}

__global__ __launch_bounds__(1024) void finalize_kernel(
    const float* __restrict__ S1, const float* __restrict__ L1, const float* __restrict__ P1,
    const float* __restrict__ S2, const float* __restrict__ P2,
    const float* __restrict__ mask, const float* __restrict__ adv, float* __restrict__ out) {
  __shared__ float red[12];
  int tid = threadIdx.x;
  int lane = tid & 63;
  if (tid < 12) red[tid] = 0.f;
  __syncthreads();

  float loss_num = 0.f, mask_sum = 0.f, ptl_sum = 0.f, lpm_sum = 0.f;
  float klb[4] = {0.f, 0.f, 0.f, 0.f}, mb[4] = {0.f, 0.f, 0.f, 0.f};
#pragma unroll
  for (int k = 0; k < 4; ++k) {
    int t = k * 1024 + tid;  // batch index b == k exactly
    float lse1 = logf(S1[t]);
    float ptl = P1[t] - lse1;
    float ref_ptl = P2[t] - logf(S2[t]);
    float d = ref_ptl - ptl;
    float kl = expf(d) - d - 1.f;
    float m = mask[t];
    float a = adv[k];
    // coef_1 = exp(ptl - stopgrad(ptl)) = 1; coef_2 = clip(1,...) = 1
    // per_token_loss = -min(adv, adv) + BETA*kl = -adv + BETA*kl
    loss_num += (-a + BETA * kl) * m;
    mask_sum += m;
    ptl_sum += ptl;
    lpm_sum += L1[t] * (1.f / (float)N_VOC) - lse1;
    klb[k] += kl * m;
    mb[k] += m;
  }
  float vals[12] = {loss_num, mask_sum, ptl_sum, lpm_sum,
                    klb[0], klb[1], klb[2], klb[3],
                    mb[0],  mb[1],  mb[2],  mb[3]};
#pragma unroll
  for (int v = 0; v < 12; ++v) {
    float xv = vals[v];
#pragma unroll
    for (int mk = 32; mk >= 1; mk >>= 1) xv += __shfl_xor(xv, mk);
    if (lane == 0) atomicAdd(&red[v], xv);
  }
  __syncthreads();
  if (tid == 0) {
    float loss = red[0] / fmaxf(red[1], 1.f);
    float km = 0.f;
#pragma unroll
    for (int b = 0; b < 4; ++b) km += red[4 + b] / fmaxf(red[8 + b], 1.f);
    out[0] = loss;                       // loss
    out[1] = red[2] * (1.f / 4096.f);    // per_token_logps.mean()
    out[2] = red[3] * (1.f / 4096.f);    // log_probs.mean()
    out[3] = km * 0.25f;                 // kl_metric
  }
}

extern "C" void kernel_launch(void* const* d_in, const int* in_sizes, int n_in,
                              void* d_out, int out_size, void* d_ws, size_t ws_size,
                              hipStream_t stream) {
  const float* x = (const float*)d_in[0];
  const float* W = (const float*)d_in[1];
  const float* ref_W = (const float*)d_in[2];
  const float* ref_x = (const float*)d_in[3];
  const int* ids = (const int*)d_in[4];
  const float* mask = (const float*)d_in[5];
  const float* adv = (const float*)d_in[6];
  float* out = (float*)d_out;

  // Workspace layout: [ Wq8 65.5MB | xq8 8.4MB | accum 96KB ]  (~74MB)
  char* ws = (char*)d_ws;
  unsigned char* Wq = (unsigned char*)ws;
  unsigned char* xq = (unsigned char*)(ws + (size_t)N_VOC * K_DIM);
  float* accum = (float*)(ws + (size_t)N_VOC * K_DIM + (size_t)M_TOK * K_DIM);
  float* S1 = accum;
  float* L1 = accum + 4096;
  float* P1 = accum + 8192;
  float* S2 = accum + 12288;
  float* L2 = accum + 16384;
  float* P2 = accum + 20480;

  hipMemsetAsync(accum, 0, 6 * 4096 * sizeof(float), stream);

  dim3 grid(N_VOC / BN, M_TOK / BM);  // 250 x 32

  cast_f32_fp8<<<2048, 256, 0, stream>>>(W, (uint2*)Wq, N_VOC * K_DIM / 8, W_SCALE);
  cast_f32_fp8<<<512, 256, 0, stream>>>(x, (uint2*)xq, M_TOK * K_DIM / 8, 1.0f);
  gemm_stats<<<grid, 256, 0, stream>>>(xq, Wq, ids, S1, L1, P1);

  // W buffer reused for ref (stream-ordered after gemm 1)
  cast_f32_fp8<<<2048, 256, 0, stream>>>(ref_W, (uint2*)Wq, N_VOC * K_DIM / 8, W_SCALE);
  cast_f32_fp8<<<512, 256, 0, stream>>>(ref_x, (uint2*)xq, M_TOK * K_DIM / 8, 1.0f);
  gemm_stats<<<grid, 256, 0, stream>>>(xq, Wq, ids, S2, L2, P2);

  finalize_kernel<<<1, 1024, 0, stream>>>(S1, L1, P1, S2, P2, mask, adv, out);
}